// Round 3
// baseline (99.536 us; speedup 1.0000x reference)
//
#include <hip/hip_runtime.h>
#include <hip/hip_bf16.h>

using bf16x8 = __attribute__((ext_vector_type(8))) short;
using f32x4  = __attribute__((ext_vector_type(4))) float;
using u16x8  = __attribute__((ext_vector_type(8))) unsigned short;

static __device__ __forceinline__ float bf2f(unsigned short u) {
    union { unsigned int i; float f; } v; v.i = ((unsigned int)u) << 16; return v.f;
}
static __device__ __forceinline__ unsigned short f2bf(float f) {
    __hip_bfloat16 h = __float2bfloat16(f);
    return *reinterpret_cast<unsigned short*>(&h);
}

__device__ __forceinline__ int lower_bound_i(const int* __restrict__ a, int n, int v) {
    int lo = 0, hi = n;
    while (lo < hi) {
        int mid = (lo + hi) >> 1;
        if (a[mid] < v) lo = mid + 1; else hi = mid;
    }
    return lo;
}

// ===========================================================================
// FAST PATH
// ===========================================================================
// Table layout after prep (per side): 8 slabs of 32 columns, slice-major:
//   emb16[slice][row][32]  (slab = 40960*32 u16 = 2.62 MB, contiguous)

#define NROW 40960
#define NSLICE 8
#define SLICEW 32   // columns per slice

// Prep: f32->bf16 slice-major tables, MFMA-packed W1/W2, segment bounds.
__global__ __launch_bounds__(256)
void nnue_prep(const float* __restrict__ wemb, const float* __restrict__ bemb,
               const float* __restrict__ W1, const float* __restrict__ W2,
               const int* __restrict__ wbatch, const int* __restrict__ bbatch,
               unsigned short* __restrict__ wemb16, unsigned short* __restrict__ bemb16,
               unsigned short* __restrict__ W1p, unsigned short* __restrict__ W2p,
               int* __restrict__ segs, long long groups, int n_act, int B)
{
    const long long r0 = groups;            // wemb groups (8 elems each)
    const long long r1 = 2 * groups;        // bemb groups
    const long long r2 = r1 + 8192;         // W1p groups: 128 frags x 64 lanes
    const long long r3 = r2 + 1024;         // W2p groups: 16 frags x 64 lanes
    const long long r4 = r3 + 2LL * (B + 1);// seg bounds
    const long long stride = (long long)gridDim.x * blockDim.x;

    for (long long t = (long long)blockIdx.x * blockDim.x + threadIdx.x;
         t < r4; t += stride) {
        if (t < r1) {
            const int w = (t < r0);
            const long long g = w ? t : (t - r0);
            const float* src = (w ? wemb : bemb) + g * 8;
            const int row  = (int)(g >> 5);
            const int col0 = ((int)g & 31) * 8;
            unsigned short* dst = (w ? wemb16 : bemb16)
                + (size_t)(col0 >> 5) * NROW * SLICEW
                + (size_t)row * SLICEW + (col0 & 31);
            const float4 a = *(const float4*)(src);
            const float4 b = *(const float4*)(src + 4);
            u16x8 o;
            o[0] = f2bf(a.x); o[1] = f2bf(a.y); o[2] = f2bf(a.z); o[3] = f2bf(a.w);
            o[4] = f2bf(b.x); o[5] = f2bf(b.y); o[6] = f2bf(b.z); o[7] = f2bf(b.w);
            *(u16x8*)dst = o;
        } else if (t < r2) {
            // W1p[(f*64+l)*8+i] = bf16(W1[kc*32+(l>>4)*8+i][nc*16+(l&15)]), f=kc*8+nc
            const int u = (int)(t - r1);
            const int f = u >> 6, l = u & 63;
            const int kc = f >> 3, nc = f & 7;
            const int krow = kc * 32 + (l >> 4) * 8;
            const int col  = nc * 16 + (l & 15);
            u16x8 o;
            #pragma unroll
            for (int i = 0; i < 8; ++i) o[i] = f2bf(W1[(size_t)(krow + i) * 128 + col]);
            *(u16x8*)(W1p + (size_t)u * 8) = o;
        } else if (t < r3) {
            const int u = (int)(t - r2);
            const int f = u >> 6, l = u & 63;
            const int kc = f >> 2, nc = f & 3;
            const int krow = kc * 32 + (l >> 4) * 8;
            const int col  = nc * 16 + (l & 15);
            u16x8 o;
            #pragma unroll
            for (int i = 0; i < 8; ++i) o[i] = f2bf(W2[(size_t)(krow + i) * 64 + col]);
            *(u16x8*)(W2p + (size_t)u * 8) = o;
        } else {
            const int u = (int)(t - r3);
            const int side = u / (B + 1);
            const int b = u - side * (B + 1);
            const int* bat = side ? bbatch : wbatch;
            segs[u] = lower_bound_i(bat, n_act, b);
        }
    }
}

// Accum, XCD-sliced: task = (b, side, slice). slice = blockIdx.x & 7 so all
// blocks for slice j land on XCD j (round-robin dispatch heuristic) and the
// per-XCD gather working set is 42MB/8 = 5.25 MB (~L2-resident).
// Block 256 = 4 waves; wave w -> task (g*4+w). Lane: rg=lane>>3 (row group),
// cl=lane&7 (8B column chunk). 8 rows in flight, 4-deep unroll.
__global__ __launch_bounds__(256)
void nnue_accum16s(const int* __restrict__ widx, const int* __restrict__ bidx,
                   const int* __restrict__ stm,
                   const unsigned short* __restrict__ wemb16,
                   const unsigned short* __restrict__ bemb16,
                   const int* __restrict__ segs,
                   unsigned short* __restrict__ x16, int B)
{
    const int wave = threadIdx.x >> 6, lane = threadIdx.x & 63;
    const int slice = blockIdx.x & 7;
    const int g = blockIdx.x >> 3;
    const int t = g * 4 + wave;
    const int b = t >> 1, side = t & 1;

    const int* __restrict__ idx = side ? bidx : widx;
    const unsigned short* __restrict__ slab =
        (side ? bemb16 : wemb16) + (size_t)slice * NROW * SLICEW;
    const int* __restrict__ sg = segs + side * (B + 1);

    const int rs = sg[b], re = sg[b + 1];
    const int rg = lane >> 3, cl = lane & 7;
    const unsigned short* __restrict__ sp = slab + cl * 4;

    float4 s = make_float4(0.f, 0.f, 0.f, 0.f);
    int r = rs + rg;
    for (; r + 24 < re; r += 32) {
        const int i0 = idx[r], i1 = idx[r + 8], i2 = idx[r + 16], i3 = idx[r + 24];
        const ushort4 v0 = *(const ushort4*)(sp + (size_t)i0 * SLICEW);
        const ushort4 v1 = *(const ushort4*)(sp + (size_t)i1 * SLICEW);
        const ushort4 v2 = *(const ushort4*)(sp + (size_t)i2 * SLICEW);
        const ushort4 v3 = *(const ushort4*)(sp + (size_t)i3 * SLICEW);
        s.x += bf2f(v0.x); s.y += bf2f(v0.y); s.z += bf2f(v0.z); s.w += bf2f(v0.w);
        s.x += bf2f(v1.x); s.y += bf2f(v1.y); s.z += bf2f(v1.z); s.w += bf2f(v1.w);
        s.x += bf2f(v2.x); s.y += bf2f(v2.y); s.z += bf2f(v2.z); s.w += bf2f(v2.w);
        s.x += bf2f(v3.x); s.y += bf2f(v3.y); s.z += bf2f(v3.z); s.w += bf2f(v3.w);
    }
    for (; r < re; r += 8) {
        const int i0 = idx[r];
        const ushort4 v0 = *(const ushort4*)(sp + (size_t)i0 * SLICEW);
        s.x += bf2f(v0.x); s.y += bf2f(v0.y); s.z += bf2f(v0.z); s.w += bf2f(v0.w);
    }

    // reduce across row groups (lane bits 3,4,5)
    #pragma unroll
    for (int d = 8; d <= 32; d <<= 1) {
        s.x += __shfl_xor(s.x, d, 64);
        s.y += __shfl_xor(s.y, d, 64);
        s.z += __shfl_xor(s.z, d, 64);
        s.w += __shfl_xor(s.w, d, 64);
    }

    if (rg == 0) {
        const int off = (stm[b] == 0) ? (side ? 0 : 256) : (side ? 256 : 0);
        ushort4 o;
        o.x = f2bf(s.x); o.y = f2bf(s.y); o.z = f2bf(s.z); o.w = f2bf(s.w);
        *(ushort4*)(x16 + (size_t)b * 512 + off + slice * SLICEW + cl * 4) = o;
    }
}

// Fused MLP: layer1 (512->128) + layer2 (128->64) via bf16 MFMA,
// layer3 (64->32) + output dot on VALU. 32 rows/block, 4 waves.
__global__ __launch_bounds__(256)
void nnue_mlp16(const unsigned short* __restrict__ x16,
                const unsigned short* __restrict__ W1p, const float* __restrict__ b1,
                const unsigned short* __restrict__ W2p, const float* __restrict__ b2,
                const float* __restrict__ W3, const float* __restrict__ b3,
                const float* __restrict__ Wo, const float* __restrict__ bo,
                float* __restrict__ out, int B)
{
    __shared__ unsigned short h1s[32 * 128];  // bf16, XOR-swizzled 16B granules
    __shared__ float h2s[32][68];             // f32, padded
    __shared__ float W3s[64 * 32];

    const int tid = threadIdx.x, wave = tid >> 6, lane = tid & 63;
    const int row0 = blockIdx.x * 32;
    const int m = lane & 15, kg = lane >> 4;

    for (int i = tid; i < 64 * 32; i += 256) W3s[i] = W3[i];

    // ---- Layer 1: wave (wr, wc) computes rows [16wr,+16) x cols [64wc,+64)
    {
        const int wr = wave >> 1, wc = wave & 1;
        f32x4 acc[4] = {{0,0,0,0},{0,0,0,0},{0,0,0,0},{0,0,0,0}};
        const unsigned short* xrow = x16 + (size_t)(row0 + wr * 16 + m) * 512;
        #pragma unroll
        for (int kc = 0; kc < 16; ++kc) {
            const bf16x8 a = *(const bf16x8*)(xrow + kc * 32 + kg * 8);
            #pragma unroll
            for (int nc = 0; nc < 4; ++nc) {
                const bf16x8 bb = *(const bf16x8*)(W1p + (size_t)((kc * 8 + wc * 4 + nc) * 64 + lane) * 8);
                acc[nc] = __builtin_amdgcn_mfma_f32_16x16x32_bf16(a, bb, acc[nc], 0, 0, 0);
            }
        }
        #pragma unroll
        for (int nc = 0; nc < 4; ++nc) {
            const int col = wc * 64 + nc * 16 + m;
            const float bias = b1[col];
            #pragma unroll
            for (int reg = 0; reg < 4; ++reg) {
                const int row = wr * 16 + kg * 4 + reg;
                const float v = fmaxf(acc[nc][reg] + bias, 0.f);
                h1s[row * 128 + (((col >> 3) ^ (row & 15)) << 3) + (col & 7)] = f2bf(v);
            }
        }
    }
    __syncthreads();

    // ---- Layer 2: wave (mr, wc2): rows [16mr,+16) x cols [32wc2,+32), K=128
    {
        const int mr = wave >> 1, wc2 = wave & 1;
        f32x4 acc2[2] = {{0,0,0,0},{0,0,0,0}};
        const int row = mr * 16 + m;
        #pragma unroll
        for (int kc = 0; kc < 4; ++kc) {
            const int g = (kc * 4 + kg) ^ (row & 15);
            const bf16x8 a = *(const bf16x8*)&h1s[row * 128 + g * 8];
            #pragma unroll
            for (int ncl = 0; ncl < 2; ++ncl) {
                const bf16x8 bb = *(const bf16x8*)(W2p + (size_t)((kc * 4 + wc2 * 2 + ncl) * 64 + lane) * 8);
                acc2[ncl] = __builtin_amdgcn_mfma_f32_16x16x32_bf16(a, bb, acc2[ncl], 0, 0, 0);
            }
        }
        #pragma unroll
        for (int ncl = 0; ncl < 2; ++ncl) {
            const int col2 = wc2 * 32 + ncl * 16 + m;
            const float bias = b2[col2];
            #pragma unroll
            for (int reg = 0; reg < 4; ++reg) {
                const int row2 = mr * 16 + kg * 4 + reg;
                h2s[row2][col2] = fmaxf(acc2[ncl][reg] + bias, 0.f);
            }
        }
    }
    __syncthreads();

    // ---- Layer 3 + output
    {
        const int col3 = lane & 31, rsel = lane >> 5;
        const int rbase = wave * 8 + rsel * 4;
        float acc3[4];
        const float bias3 = b3[col3];
        #pragma unroll
        for (int ri = 0; ri < 4; ++ri) acc3[ri] = bias3;
        #pragma unroll
        for (int k = 0; k < 64; k += 4) {
            float4 w;
            w.x = W3s[(k + 0) * 32 + col3];
            w.y = W3s[(k + 1) * 32 + col3];
            w.z = W3s[(k + 2) * 32 + col3];
            w.w = W3s[(k + 3) * 32 + col3];
            #pragma unroll
            for (int ri = 0; ri < 4; ++ri) {
                const float4 h = *(const float4*)&h2s[rbase + ri][k];
                acc3[ri] = fmaf(h.x, w.x, fmaf(h.y, w.y, fmaf(h.z, w.z, fmaf(h.w, w.w, acc3[ri]))));
            }
        }
        const float wo = Wo[col3], bo0 = bo[0];
        #pragma unroll
        for (int ri = 0; ri < 4; ++ri) {
            float v = fmaxf(acc3[ri], 0.f) * wo;
            v += __shfl_xor(v, 16, 64);
            v += __shfl_xor(v, 8, 64);
            v += __shfl_xor(v, 4, 64);
            v += __shfl_xor(v, 2, 64);
            v += __shfl_xor(v, 1, 64);
            if (col3 == 0) out[row0 + rbase + ri] = v + bo0;
        }
    }
}

// ===========================================================================
// FALLBACK (f32 path, used only if ws_size is too small)
// ===========================================================================

__global__ __launch_bounds__(64)
void nnue_accum_f32(const int* __restrict__ widx, const int* __restrict__ bidx,
                    const int* __restrict__ wbatch, const int* __restrict__ bbatch,
                    const int* __restrict__ stm,
                    const float* __restrict__ wemb, const float* __restrict__ bemb,
                    float* __restrict__ x, int n_act)
{
    const int b = blockIdx.x, side = blockIdx.y;
    const int*   __restrict__ idx   = side ? bidx   : widx;
    const int*   __restrict__ batch = side ? bbatch : wbatch;
    const float* __restrict__ emb   = side ? bemb   : wemb;
    const int start = lower_bound_i(batch, n_act, b);
    const int end   = lower_bound_i(batch, n_act, b + 1);
    const int c = threadIdx.x << 2;
    float4 s0 = make_float4(0.f, 0.f, 0.f, 0.f);
    float4 s1 = s0, s2 = s0, s3 = s0;
    int r = start;
    for (; r + 4 <= end; r += 4) {
        const float4 v0 = *(const float4*)(emb + (size_t)idx[r + 0] * 256 + c);
        const float4 v1 = *(const float4*)(emb + (size_t)idx[r + 1] * 256 + c);
        const float4 v2 = *(const float4*)(emb + (size_t)idx[r + 2] * 256 + c);
        const float4 v3 = *(const float4*)(emb + (size_t)idx[r + 3] * 256 + c);
        s0.x += v0.x; s0.y += v0.y; s0.z += v0.z; s0.w += v0.w;
        s1.x += v1.x; s1.y += v1.y; s1.z += v1.z; s1.w += v1.w;
        s2.x += v2.x; s2.y += v2.y; s2.z += v2.z; s2.w += v2.w;
        s3.x += v3.x; s3.y += v3.y; s3.z += v3.z; s3.w += v3.w;
    }
    for (; r < end; ++r) {
        const float4 v0 = *(const float4*)(emb + (size_t)idx[r] * 256 + c);
        s0.x += v0.x; s0.y += v0.y; s0.z += v0.z; s0.w += v0.w;
    }
    s0.x += s1.x + s2.x + s3.x; s0.y += s1.y + s2.y + s3.y;
    s0.z += s1.z + s2.z + s3.z; s0.w += s1.w + s2.w + s3.w;
    const int off = (stm[b] == 0) ? (side ? 0 : 256) : (side ? 256 : 0);
    *(float4*)(x + (size_t)b * 512 + off + c) = s0;
}

__global__ __launch_bounds__(256)
void nnue_layer1_f32(const float* __restrict__ x, const float* __restrict__ W1,
                     const float* __restrict__ b1, float* __restrict__ h1, int B)
{
    __shared__ float xs[16][512];
    const int tid = threadIdx.x;
    const int row0 = blockIdx.x * 16;
    #pragma unroll
    for (int i = 0; i < 8; ++i) {
        const int e = (i * 256 + tid) * 4;
        const int rr = e >> 9, cc = e & 511;
        if (row0 + rr < B)
            *(float4*)&xs[rr][cc] = *(const float4*)(x + (size_t)(row0 + rr) * 512 + cc);
    }
    __syncthreads();
    const int wave = tid >> 6, lane = tid & 63;
    const int j2 = lane * 2, wrow = wave * 4;
    float2 acc[4];
    #pragma unroll
    for (int r2 = 0; r2 < 4; ++r2) { acc[r2].x = b1[j2]; acc[r2].y = b1[j2 + 1]; }
    for (int k = 0; k < 512; k += 4) {
        float4 xv[4];
        #pragma unroll
        for (int r2 = 0; r2 < 4; ++r2) xv[r2] = *(const float4*)&xs[wrow + r2][k];
        #pragma unroll
        for (int kk = 0; kk < 4; ++kk) {
            const float2 w = *(const float2*)(W1 + (size_t)(k + kk) * 128 + j2);
            #pragma unroll
            for (int r2 = 0; r2 < 4; ++r2) {
                const float xvv = (&xv[r2].x)[kk];
                acc[r2].x = fmaf(xvv, w.x, acc[r2].x);
                acc[r2].y = fmaf(xvv, w.y, acc[r2].y);
            }
        }
    }
    #pragma unroll
    for (int r2 = 0; r2 < 4; ++r2) {
        const int row = row0 + wrow + r2;
        if (row < B) {
            float2 o;
            o.x = fmaxf(acc[r2].x, 0.f); o.y = fmaxf(acc[r2].y, 0.f);
            *(float2*)(h1 + (size_t)row * 128 + j2) = o;
        }
    }
}

__global__ __launch_bounds__(256)
void nnue_tail_f32(const float* __restrict__ h1,
                   const float* __restrict__ W2, const float* __restrict__ b2,
                   const float* __restrict__ W3, const float* __restrict__ b3,
                   const float* __restrict__ Wo, const float* __restrict__ bo,
                   float* __restrict__ out, int B)
{
    __shared__ float W2s[128 * 64];
    __shared__ float W3s[64 * 32];
    __shared__ float Wos[32];
    __shared__ float h1row[4][128];
    __shared__ float h2row[4][64];
    const int tid = threadIdx.x;
    for (int i = tid; i < 128 * 64; i += 256) W2s[i] = W2[i];
    for (int i = tid; i < 64 * 32; i += 256)  W3s[i] = W3[i];
    if (tid < 32) Wos[tid] = Wo[tid];
    __syncthreads();
    const int wave = tid >> 6, lane = tid & 63;
    const float bias2 = b2[lane];
    const float bias3 = (lane < 32) ? b3[lane] : 0.f;
    const float wo = (lane < 32) ? Wos[lane] : 0.f;
    const float bo0 = bo[0];
    #pragma unroll 1
    for (int it = 0; it < 8; ++it) {
        const int row = blockIdx.x * 32 + wave * 8 + it;
        if (row >= B) break;
        h1row[wave][lane]      = h1[(size_t)row * 128 + lane];
        h1row[wave][lane + 64] = h1[(size_t)row * 128 + 64 + lane];
        float acc = bias2;
        #pragma unroll 8
        for (int k = 0; k < 128; ++k)
            acc = fmaf(h1row[wave][k], W2s[k * 64 + lane], acc);
        acc = fmaxf(acc, 0.f);
        h2row[wave][lane] = acc;
        float acc3 = 0.f;
        if (lane < 32) {
            acc3 = bias3;
            #pragma unroll 8
            for (int k = 0; k < 64; ++k)
                acc3 = fmaf(h2row[wave][k], W3s[k * 32 + lane], acc3);
            acc3 = fmaxf(acc3, 0.f) * wo;
        }
        #pragma unroll
        for (int sft = 32; sft >= 1; sft >>= 1)
            acc3 += __shfl_xor(acc3, sft, 64);
        if (lane == 0) out[row] = acc3 + bo0;
    }
}

// ===========================================================================

extern "C" void kernel_launch(void* const* d_in, const int* in_sizes, int n_in,
                              void* d_out, int out_size, void* d_ws, size_t ws_size,
                              hipStream_t stream)
{
    const int*   widx   = (const int*)d_in[0];
    const int*   bidx   = (const int*)d_in[1];
    const int*   wbatch = (const int*)d_in[2];
    const int*   bbatch = (const int*)d_in[3];
    const int*   stm    = (const int*)d_in[4];
    const float* wemb   = (const float*)d_in[5];
    const float* bemb   = (const float*)d_in[6];
    const float* W1     = (const float*)d_in[7];
    const float* b1     = (const float*)d_in[8];
    const float* W2     = (const float*)d_in[9];
    const float* b2     = (const float*)d_in[10];
    const float* W3     = (const float*)d_in[11];
    const float* b3     = (const float*)d_in[12];
    const float* Wo     = (const float*)d_in[13];
    const float* bo     = (const float*)d_in[14];

    const int n_act = in_sizes[0];
    const int B     = in_sizes[4];
    const size_t embN = (size_t)in_sizes[5];   // 40960*256

    // workspace layout (fast path)
    char* p = (char*)d_ws;
    unsigned short* wemb16 = (unsigned short*)p; p += embN * 2;
    unsigned short* bemb16 = (unsigned short*)p; p += embN * 2;
    unsigned short* x16    = (unsigned short*)p; p += (size_t)B * 512 * 2;
    unsigned short* W1p    = (unsigned short*)p; p += 65536 * 2;
    unsigned short* W2p    = (unsigned short*)p; p += 8192 * 2;
    int*            segs   = (int*)p;            p += (size_t)2 * (B + 1) * 4;
    const size_t needed = (size_t)(p - (char*)d_ws);

    const bool fast = (ws_size >= needed) && (B % 32) == 0 &&
                      embN == (size_t)NROW * 256;

    if (fast) {
        const long long groups = (long long)(embN / 8);
        nnue_prep<<<2048, 256, 0, stream>>>(wemb, bemb, W1, W2, wbatch, bbatch,
                                            wemb16, bemb16, W1p, W2p, segs,
                                            groups, n_act, B);
        // blocks: (2*B tasks / 4 waves) * 8 slices
        const int nblk = (2 * B / 4) * NSLICE;
        nnue_accum16s<<<nblk, 256, 0, stream>>>(widx, bidx, stm, wemb16, bemb16,
                                                segs, x16, B);
        nnue_mlp16<<<B / 32, 256, 0, stream>>>(x16, W1p, b1, W2p, b2,
                                               W3, b3, Wo, bo, (float*)d_out, B);
    } else {
        float* x  = (float*)d_ws;
        float* h1 = x + (size_t)B * 512;
        dim3 gA(B, 2);
        nnue_accum_f32<<<gA, 64, 0, stream>>>(widx, bidx, wbatch, bbatch, stm,
                                              wemb, bemb, x, n_act);
        nnue_layer1_f32<<<(B + 15) / 16, 256, 0, stream>>>(x, W1, b1, h1, B);
        nnue_tail_f32<<<(B + 31) / 32, 256, 0, stream>>>(h1, W2, b2, W3, b3, Wo, bo,
                                                         (float*)d_out, B);
    }
}

// Round 4
// 73.121 us; speedup vs baseline: 1.3612x; 1.3612x over previous
//
#include <hip/hip_runtime.h>
#include <hip/hip_bf16.h>

using bf16x8 = __attribute__((ext_vector_type(8))) short;
using f32x4  = __attribute__((ext_vector_type(4))) float;
using u16x8  = __attribute__((ext_vector_type(8))) unsigned short;

static __device__ __forceinline__ float bf2f(unsigned short u) {
    union { unsigned int i; float f; } v; v.i = ((unsigned int)u) << 16; return v.f;
}
static __device__ __forceinline__ unsigned short f2bf(float f) {
    __hip_bfloat16 h = __float2bfloat16(f);
    return *reinterpret_cast<unsigned short*>(&h);
}

__device__ __forceinline__ int lower_bound_i(const int* __restrict__ a, int n, int v) {
    int lo = 0, hi = n;
    while (lo < hi) {
        int mid = (lo + hi) >> 1;
        if (a[mid] < v) lo = mid + 1; else hi = mid;
    }
    return lo;
}

// ===========================================================================
// FAST PATH
// ===========================================================================
// Table layout after prep (per side): 8 slabs of 32 columns, slice-major:
//   emb16[slice][row][32]  (slab = 40960*32 u16 = 2.62 MB, contiguous)

#define NROW 40960
#define NSLICE 8
#define SLICEW 32   // columns per slice

// Prep: f32->bf16 slice-major tables, MFMA-packed W1/W2, segment bounds.
__global__ __launch_bounds__(256)
void nnue_prep(const float* __restrict__ wemb, const float* __restrict__ bemb,
               const float* __restrict__ W1, const float* __restrict__ W2,
               const int* __restrict__ wbatch, const int* __restrict__ bbatch,
               unsigned short* __restrict__ wemb16, unsigned short* __restrict__ bemb16,
               unsigned short* __restrict__ W1p, unsigned short* __restrict__ W2p,
               int* __restrict__ segs, long long groups, int n_act, int B)
{
    const long long r0 = groups;            // wemb groups (8 elems each)
    const long long r1 = 2 * groups;        // bemb groups
    const long long r2 = r1 + 8192;         // W1p groups: 128 frags x 64 lanes
    const long long r3 = r2 + 1024;         // W2p groups: 16 frags x 64 lanes
    const long long r4 = r3 + 2LL * (B + 1);// seg bounds
    const long long stride = (long long)gridDim.x * blockDim.x;

    for (long long t = (long long)blockIdx.x * blockDim.x + threadIdx.x;
         t < r4; t += stride) {
        if (t < r1) {
            const int w = (t < r0);
            const long long g = w ? t : (t - r0);
            const float* src = (w ? wemb : bemb) + g * 8;
            const int row  = (int)(g >> 5);
            const int col0 = ((int)g & 31) * 8;
            unsigned short* dst = (w ? wemb16 : bemb16)
                + (size_t)(col0 >> 5) * NROW * SLICEW
                + (size_t)row * SLICEW + (col0 & 31);
            const float4 a = *(const float4*)(src);
            const float4 b = *(const float4*)(src + 4);
            u16x8 o;
            o[0] = f2bf(a.x); o[1] = f2bf(a.y); o[2] = f2bf(a.z); o[3] = f2bf(a.w);
            o[4] = f2bf(b.x); o[5] = f2bf(b.y); o[6] = f2bf(b.z); o[7] = f2bf(b.w);
            *(u16x8*)dst = o;
        } else if (t < r2) {
            // W1p[(f*64+l)*8+i] = bf16(W1[kc*32+(l>>4)*8+i][nc*16+(l&15)]), f=kc*8+nc
            const int u = (int)(t - r1);
            const int f = u >> 6, l = u & 63;
            const int kc = f >> 3, nc = f & 7;
            const int krow = kc * 32 + (l >> 4) * 8;
            const int col  = nc * 16 + (l & 15);
            u16x8 o;
            #pragma unroll
            for (int i = 0; i < 8; ++i) o[i] = f2bf(W1[(size_t)(krow + i) * 128 + col]);
            *(u16x8*)(W1p + (size_t)u * 8) = o;
        } else if (t < r3) {
            const int u = (int)(t - r2);
            const int f = u >> 6, l = u & 63;
            const int kc = f >> 2, nc = f & 3;
            const int krow = kc * 32 + (l >> 4) * 8;
            const int col  = nc * 16 + (l & 15);
            u16x8 o;
            #pragma unroll
            for (int i = 0; i < 8; ++i) o[i] = f2bf(W2[(size_t)(krow + i) * 64 + col]);
            *(u16x8*)(W2p + (size_t)u * 8) = o;
        } else {
            const int u = (int)(t - r3);
            const int side = u / (B + 1);
            const int b = u - side * (B + 1);
            const int* bat = side ? bbatch : wbatch;
            segs[u] = lower_bound_i(bat, n_act, b);
        }
    }
}

// Accum, XCD-sliced v2.
// Partition = (side, slice of 32 cols). bid = side*(nchunk*8) + chunk*8 + slice
// so XCD = bid&7 = slice (affinity) and the two sides are temporally separated
// (per-XCD live set = one 2.62 MB slab, L2-resident).
// Block 256 = 4 waves x 8 batches/wave. Lane: rg=lane>>3 picks the batch,
// cl=lane&7 picks 4 columns (8B). Each 8-lane group owns one batch's slice
// end-to-end: no cross-lane reduction. 4-deep unroll for ILP.
__global__ __launch_bounds__(256)
void nnue_accum16v(const int* __restrict__ widx, const int* __restrict__ bidx,
                   const int* __restrict__ stm,
                   const unsigned short* __restrict__ wemb16,
                   const unsigned short* __restrict__ bemb16,
                   const int* __restrict__ segs,
                   unsigned short* __restrict__ x16, int B, int nchunk)
{
    const int wave = threadIdx.x >> 6, lane = threadIdx.x & 63;
    const int slice = blockIdx.x & 7;
    const int rest  = blockIdx.x >> 3;
    const int side  = (rest >= nchunk) ? 1 : 0;
    const int chunk = rest - side * nchunk;

    const int rg = lane >> 3, cl = lane & 7;
    const int b  = chunk * 32 + wave * 8 + rg;

    const int* __restrict__ idx = side ? bidx : widx;
    const unsigned short* __restrict__ sp =
        (side ? bemb16 : wemb16) + (size_t)slice * NROW * SLICEW + cl * 4;
    const int* __restrict__ sg = segs + side * (B + 1);

    const int rs = sg[b], re = sg[b + 1];

    float4 s = make_float4(0.f, 0.f, 0.f, 0.f);
    int r = rs;
    for (; r + 4 <= re; r += 4) {
        const int i0 = idx[r], i1 = idx[r + 1], i2 = idx[r + 2], i3 = idx[r + 3];
        const ushort4 v0 = *(const ushort4*)(sp + (size_t)i0 * SLICEW);
        const ushort4 v1 = *(const ushort4*)(sp + (size_t)i1 * SLICEW);
        const ushort4 v2 = *(const ushort4*)(sp + (size_t)i2 * SLICEW);
        const ushort4 v3 = *(const ushort4*)(sp + (size_t)i3 * SLICEW);
        s.x += bf2f(v0.x); s.y += bf2f(v0.y); s.z += bf2f(v0.z); s.w += bf2f(v0.w);
        s.x += bf2f(v1.x); s.y += bf2f(v1.y); s.z += bf2f(v1.z); s.w += bf2f(v1.w);
        s.x += bf2f(v2.x); s.y += bf2f(v2.y); s.z += bf2f(v2.z); s.w += bf2f(v2.w);
        s.x += bf2f(v3.x); s.y += bf2f(v3.y); s.z += bf2f(v3.z); s.w += bf2f(v3.w);
    }
    for (; r < re; ++r) {
        const ushort4 v0 = *(const ushort4*)(sp + (size_t)idx[r] * SLICEW);
        s.x += bf2f(v0.x); s.y += bf2f(v0.y); s.z += bf2f(v0.z); s.w += bf2f(v0.w);
    }

    const int off = (stm[b] == 0) ? (side ? 0 : 256) : (side ? 256 : 0);
    ushort4 o;
    o.x = f2bf(s.x); o.y = f2bf(s.y); o.z = f2bf(s.z); o.w = f2bf(s.w);
    *(ushort4*)(x16 + (size_t)b * 512 + off + slice * SLICEW + cl * 4) = o;
}

// Fused MLP: layer1 (512->128) + layer2 (128->64) via bf16 MFMA,
// layer3 (64->32) + output dot on VALU. 32 rows/block, 4 waves.
__global__ __launch_bounds__(256)
void nnue_mlp16(const unsigned short* __restrict__ x16,
                const unsigned short* __restrict__ W1p, const float* __restrict__ b1,
                const unsigned short* __restrict__ W2p, const float* __restrict__ b2,
                const float* __restrict__ W3, const float* __restrict__ b3,
                const float* __restrict__ Wo, const float* __restrict__ bo,
                float* __restrict__ out, int B)
{
    __shared__ unsigned short h1s[32 * 128];  // bf16, XOR-swizzled 16B granules
    __shared__ float h2s[32][68];             // f32, padded
    __shared__ float W3s[64 * 32];

    const int tid = threadIdx.x, wave = tid >> 6, lane = tid & 63;
    const int row0 = blockIdx.x * 32;
    const int m = lane & 15, kg = lane >> 4;

    for (int i = tid; i < 64 * 32; i += 256) W3s[i] = W3[i];

    // ---- Layer 1: wave (wr, wc) computes rows [16wr,+16) x cols [64wc,+64)
    {
        const int wr = wave >> 1, wc = wave & 1;
        f32x4 acc[4] = {{0,0,0,0},{0,0,0,0},{0,0,0,0},{0,0,0,0}};
        const unsigned short* xrow = x16 + (size_t)(row0 + wr * 16 + m) * 512;
        #pragma unroll
        for (int kc = 0; kc < 16; ++kc) {
            const bf16x8 a = *(const bf16x8*)(xrow + kc * 32 + kg * 8);
            #pragma unroll
            for (int nc = 0; nc < 4; ++nc) {
                const bf16x8 bb = *(const bf16x8*)(W1p + (size_t)((kc * 8 + wc * 4 + nc) * 64 + lane) * 8);
                acc[nc] = __builtin_amdgcn_mfma_f32_16x16x32_bf16(a, bb, acc[nc], 0, 0, 0);
            }
        }
        #pragma unroll
        for (int nc = 0; nc < 4; ++nc) {
            const int col = wc * 64 + nc * 16 + m;
            const float bias = b1[col];
            #pragma unroll
            for (int reg = 0; reg < 4; ++reg) {
                const int row = wr * 16 + kg * 4 + reg;
                const float v = fmaxf(acc[nc][reg] + bias, 0.f);
                h1s[row * 128 + (((col >> 3) ^ (row & 15)) << 3) + (col & 7)] = f2bf(v);
            }
        }
    }
    __syncthreads();

    // ---- Layer 2: wave (mr, wc2): rows [16mr,+16) x cols [32wc2,+32), K=128
    {
        const int mr = wave >> 1, wc2 = wave & 1;
        f32x4 acc2[2] = {{0,0,0,0},{0,0,0,0}};
        const int row = mr * 16 + m;
        #pragma unroll
        for (int kc = 0; kc < 4; ++kc) {
            const int g = (kc * 4 + kg) ^ (row & 15);
            const bf16x8 a = *(const bf16x8*)&h1s[row * 128 + g * 8];
            #pragma unroll
            for (int ncl = 0; ncl < 2; ++ncl) {
                const bf16x8 bb = *(const bf16x8*)(W2p + (size_t)((kc * 4 + wc2 * 2 + ncl) * 64 + lane) * 8);
                acc2[ncl] = __builtin_amdgcn_mfma_f32_16x16x32_bf16(a, bb, acc2[ncl], 0, 0, 0);
            }
        }
        #pragma unroll
        for (int ncl = 0; ncl < 2; ++ncl) {
            const int col2 = wc2 * 32 + ncl * 16 + m;
            const float bias = b2[col2];
            #pragma unroll
            for (int reg = 0; reg < 4; ++reg) {
                const int row2 = mr * 16 + kg * 4 + reg;
                h2s[row2][col2] = fmaxf(acc2[ncl][reg] + bias, 0.f);
            }
        }
    }
    __syncthreads();

    // ---- Layer 3 + output
    {
        const int col3 = lane & 31, rsel = lane >> 5;
        const int rbase = wave * 8 + rsel * 4;
        float acc3[4];
        const float bias3 = b3[col3];
        #pragma unroll
        for (int ri = 0; ri < 4; ++ri) acc3[ri] = bias3;
        #pragma unroll
        for (int k = 0; k < 64; k += 4) {
            float4 w;
            w.x = W3s[(k + 0) * 32 + col3];
            w.y = W3s[(k + 1) * 32 + col3];
            w.z = W3s[(k + 2) * 32 + col3];
            w.w = W3s[(k + 3) * 32 + col3];
            #pragma unroll
            for (int ri = 0; ri < 4; ++ri) {
                const float4 h = *(const float4*)&h2s[rbase + ri][k];
                acc3[ri] = fmaf(h.x, w.x, fmaf(h.y, w.y, fmaf(h.z, w.z, fmaf(h.w, w.w, acc3[ri]))));
            }
        }
        const float wo = Wo[col3], bo0 = bo[0];
        #pragma unroll
        for (int ri = 0; ri < 4; ++ri) {
            float v = fmaxf(acc3[ri], 0.f) * wo;
            v += __shfl_xor(v, 16, 64);
            v += __shfl_xor(v, 8, 64);
            v += __shfl_xor(v, 4, 64);
            v += __shfl_xor(v, 2, 64);
            v += __shfl_xor(v, 1, 64);
            if (col3 == 0) out[row0 + rbase + ri] = v + bo0;
        }
    }
}

// ===========================================================================
// FALLBACK (f32 path, used only if ws_size is too small)
// ===========================================================================

__global__ __launch_bounds__(64)
void nnue_accum_f32(const int* __restrict__ widx, const int* __restrict__ bidx,
                    const int* __restrict__ wbatch, const int* __restrict__ bbatch,
                    const int* __restrict__ stm,
                    const float* __restrict__ wemb, const float* __restrict__ bemb,
                    float* __restrict__ x, int n_act)
{
    const int b = blockIdx.x, side = blockIdx.y;
    const int*   __restrict__ idx   = side ? bidx   : widx;
    const int*   __restrict__ batch = side ? bbatch : wbatch;
    const float* __restrict__ emb   = side ? bemb   : wemb;
    const int start = lower_bound_i(batch, n_act, b);
    const int end   = lower_bound_i(batch, n_act, b + 1);
    const int c = threadIdx.x << 2;
    float4 s0 = make_float4(0.f, 0.f, 0.f, 0.f);
    float4 s1 = s0, s2 = s0, s3 = s0;
    int r = start;
    for (; r + 4 <= end; r += 4) {
        const float4 v0 = *(const float4*)(emb + (size_t)idx[r + 0] * 256 + c);
        const float4 v1 = *(const float4*)(emb + (size_t)idx[r + 1] * 256 + c);
        const float4 v2 = *(const float4*)(emb + (size_t)idx[r + 2] * 256 + c);
        const float4 v3 = *(const float4*)(emb + (size_t)idx[r + 3] * 256 + c);
        s0.x += v0.x; s0.y += v0.y; s0.z += v0.z; s0.w += v0.w;
        s1.x += v1.x; s1.y += v1.y; s1.z += v1.z; s1.w += v1.w;
        s2.x += v2.x; s2.y += v2.y; s2.z += v2.z; s2.w += v2.w;
        s3.x += v3.x; s3.y += v3.y; s3.z += v3.z; s3.w += v3.w;
    }
    for (; r < end; ++r) {
        const float4 v0 = *(const float4*)(emb + (size_t)idx[r] * 256 + c);
        s0.x += v0.x; s0.y += v0.y; s0.z += v0.z; s0.w += v0.w;
    }
    s0.x += s1.x + s2.x + s3.x; s0.y += s1.y + s2.y + s3.y;
    s0.z += s1.z + s2.z + s3.z; s0.w += s1.w + s2.w + s3.w;
    const int off = (stm[b] == 0) ? (side ? 0 : 256) : (side ? 256 : 0);
    *(float4*)(x + (size_t)b * 512 + off + c) = s0;
}

__global__ __launch_bounds__(256)
void nnue_layer1_f32(const float* __restrict__ x, const float* __restrict__ W1,
                     const float* __restrict__ b1, float* __restrict__ h1, int B)
{
    __shared__ float xs[16][512];
    const int tid = threadIdx.x;
    const int row0 = blockIdx.x * 16;
    #pragma unroll
    for (int i = 0; i < 8; ++i) {
        const int e = (i * 256 + tid) * 4;
        const int rr = e >> 9, cc = e & 511;
        if (row0 + rr < B)
            *(float4*)&xs[rr][cc] = *(const float4*)(x + (size_t)(row0 + rr) * 512 + cc);
    }
    __syncthreads();
    const int wave = tid >> 6, lane = tid & 63;
    const int j2 = lane * 2, wrow = wave * 4;
    float2 acc[4];
    #pragma unroll
    for (int r2 = 0; r2 < 4; ++r2) { acc[r2].x = b1[j2]; acc[r2].y = b1[j2 + 1]; }
    for (int k = 0; k < 512; k += 4) {
        float4 xv[4];
        #pragma unroll
        for (int r2 = 0; r2 < 4; ++r2) xv[r2] = *(const float4*)&xs[wrow + r2][k];
        #pragma unroll
        for (int kk = 0; kk < 4; ++kk) {
            const float2 w = *(const float2*)(W1 + (size_t)(k + kk) * 128 + j2);
            #pragma unroll
            for (int r2 = 0; r2 < 4; ++r2) {
                const float xvv = (&xv[r2].x)[kk];
                acc[r2].x = fmaf(xvv, w.x, acc[r2].x);
                acc[r2].y = fmaf(xvv, w.y, acc[r2].y);
            }
        }
    }
    #pragma unroll
    for (int r2 = 0; r2 < 4; ++r2) {
        const int row = row0 + wrow + r2;
        if (row < B) {
            float2 o;
            o.x = fmaxf(acc[r2].x, 0.f); o.y = fmaxf(acc[r2].y, 0.f);
            *(float2*)(h1 + (size_t)row * 128 + j2) = o;
        }
    }
}

__global__ __launch_bounds__(256)
void nnue_tail_f32(const float* __restrict__ h1,
                   const float* __restrict__ W2, const float* __restrict__ b2,
                   const float* __restrict__ W3, const float* __restrict__ b3,
                   const float* __restrict__ Wo, const float* __restrict__ bo,
                   float* __restrict__ out, int B)
{
    __shared__ float W2s[128 * 64];
    __shared__ float W3s[64 * 32];
    __shared__ float Wos[32];
    __shared__ float h1row[4][128];
    __shared__ float h2row[4][64];
    const int tid = threadIdx.x;
    for (int i = tid; i < 128 * 64; i += 256) W2s[i] = W2[i];
    for (int i = tid; i < 64 * 32; i += 256)  W3s[i] = W3[i];
    if (tid < 32) Wos[tid] = Wo[tid];
    __syncthreads();
    const int wave = tid >> 6, lane = tid & 63;
    const float bias2 = b2[lane];
    const float bias3 = (lane < 32) ? b3[lane] : 0.f;
    const float wo = (lane < 32) ? Wos[lane] : 0.f;
    const float bo0 = bo[0];
    #pragma unroll 1
    for (int it = 0; it < 8; ++it) {
        const int row = blockIdx.x * 32 + wave * 8 + it;
        if (row >= B) break;
        h1row[wave][lane]      = h1[(size_t)row * 128 + lane];
        h1row[wave][lane + 64] = h1[(size_t)row * 128 + 64 + lane];
        float acc = bias2;
        #pragma unroll 8
        for (int k = 0; k < 128; ++k)
            acc = fmaf(h1row[wave][k], W2s[k * 64 + lane], acc);
        acc = fmaxf(acc, 0.f);
        h2row[wave][lane] = acc;
        float acc3 = 0.f;
        if (lane < 32) {
            acc3 = bias3;
            #pragma unroll 8
            for (int k = 0; k < 64; ++k)
                acc3 = fmaf(h2row[wave][k], W3s[k * 32 + lane], acc3);
            acc3 = fmaxf(acc3, 0.f) * wo;
        }
        #pragma unroll
        for (int sft = 32; sft >= 1; sft >>= 1)
            acc3 += __shfl_xor(acc3, sft, 64);
        if (lane == 0) out[row] = acc3 + bo0;
    }
}

// ===========================================================================

extern "C" void kernel_launch(void* const* d_in, const int* in_sizes, int n_in,
                              void* d_out, int out_size, void* d_ws, size_t ws_size,
                              hipStream_t stream)
{
    const int*   widx   = (const int*)d_in[0];
    const int*   bidx   = (const int*)d_in[1];
    const int*   wbatch = (const int*)d_in[2];
    const int*   bbatch = (const int*)d_in[3];
    const int*   stm    = (const int*)d_in[4];
    const float* wemb   = (const float*)d_in[5];
    const float* bemb   = (const float*)d_in[6];
    const float* W1     = (const float*)d_in[7];
    const float* b1     = (const float*)d_in[8];
    const float* W2     = (const float*)d_in[9];
    const float* b2     = (const float*)d_in[10];
    const float* W3     = (const float*)d_in[11];
    const float* b3     = (const float*)d_in[12];
    const float* Wo     = (const float*)d_in[13];
    const float* bo     = (const float*)d_in[14];

    const int n_act = in_sizes[0];
    const int B     = in_sizes[4];
    const size_t embN = (size_t)in_sizes[5];   // 40960*256

    // workspace layout (fast path)
    char* p = (char*)d_ws;
    unsigned short* wemb16 = (unsigned short*)p; p += embN * 2;
    unsigned short* bemb16 = (unsigned short*)p; p += embN * 2;
    unsigned short* x16    = (unsigned short*)p; p += (size_t)B * 512 * 2;
    unsigned short* W1p    = (unsigned short*)p; p += 65536 * 2;
    unsigned short* W2p    = (unsigned short*)p; p += 8192 * 2;
    int*            segs   = (int*)p;            p += (size_t)2 * (B + 1) * 4;
    const size_t needed = (size_t)(p - (char*)d_ws);

    const bool fast = (ws_size >= needed) && (B % 32) == 0 &&
                      embN == (size_t)NROW * 256;

    if (fast) {
        const long long groups = (long long)(embN / 8);
        nnue_prep<<<2048, 256, 0, stream>>>(wemb, bemb, W1, W2, wbatch, bbatch,
                                            wemb16, bemb16, W1p, W2p, segs,
                                            groups, n_act, B);
        // bid = side*(nchunk*8) + chunk*8 + slice; XCD = bid&7 = slice
        const int nchunk = B / 32;
        const int nblk = 2 * nchunk * NSLICE;
        nnue_accum16v<<<nblk, 256, 0, stream>>>(widx, bidx, stm, wemb16, bemb16,
                                                segs, x16, B, nchunk);
        nnue_mlp16<<<B / 32, 256, 0, stream>>>(x16, W1p, b1, W2p, b2,
                                               W3, b3, Wo, bo, (float*)d_out, B);
    } else {
        float* x  = (float*)d_ws;
        float* h1 = x + (size_t)B * 512;
        dim3 gA(B, 2);
        nnue_accum_f32<<<gA, 64, 0, stream>>>(widx, bidx, wbatch, bbatch, stm,
                                              wemb, bemb, x, n_act);
        nnue_layer1_f32<<<(B + 15) / 16, 256, 0, stream>>>(x, W1, b1, h1, B);
        nnue_tail_f32<<<(B + 31) / 32, 256, 0, stream>>>(h1, W2, b2, W3, b3, Wo, bo,
                                                         (float*)d_out, B);
    }
}

// Round 5
// 71.884 us; speedup vs baseline: 1.3847x; 1.0172x over previous
//
#include <hip/hip_runtime.h>
#include <hip/hip_bf16.h>

using bf16x8 = __attribute__((ext_vector_type(8))) short;
using f32x4  = __attribute__((ext_vector_type(4))) float;
using u16x8  = __attribute__((ext_vector_type(8))) unsigned short;

static __device__ __forceinline__ float bf2f(unsigned short u) {
    union { unsigned int i; float f; } v; v.i = ((unsigned int)u) << 16; return v.f;
}
static __device__ __forceinline__ unsigned short f2bf(float f) {
    __hip_bfloat16 h = __float2bfloat16(f);
    return *reinterpret_cast<unsigned short*>(&h);
}

__device__ __forceinline__ int lower_bound_i(const int* __restrict__ a, int n, int v) {
    int lo = 0, hi = n;
    while (lo < hi) {
        int mid = (lo + hi) >> 1;
        if (a[mid] < v) lo = mid + 1; else hi = mid;
    }
    return lo;
}

// ===========================================================================
// FAST PATH
// ===========================================================================
// No table copy. Gather directly from row-major f32 tables: a 32-col slice of
// row r is ONE aligned 128B line at r*1024 + slice*128, so XCD-affine slicing
// (XCD = bid&7 = slice) gives a 5.25 MB per-XCD line working set (~L2).

#define NSLICE 8

// Prep-lite: MFMA-pack W1/W2 (f32->bf16 fragments) + segment bounds only.
__global__ __launch_bounds__(256)
void nnue_prep_lite(const float* __restrict__ W1, const float* __restrict__ W2,
                    const int* __restrict__ wbatch, const int* __restrict__ bbatch,
                    unsigned short* __restrict__ W1p, unsigned short* __restrict__ W2p,
                    int* __restrict__ segs, int n_act, int B)
{
    const int r1 = 8192;                 // W1p items: 128 frags x 64 lanes
    const int r2 = r1 + 1024;            // W2p items: 16 frags x 64 lanes
    const int r3 = r2 + 2 * (B + 1);     // seg bounds
    const int stride = gridDim.x * blockDim.x;

    for (int t = blockIdx.x * blockDim.x + threadIdx.x; t < r3; t += stride) {
        if (t < r1) {
            // W1p[(f*64+l)*8+i] = bf16(W1[kc*32+(l>>4)*8+i][nc*16+(l&15)]), f=kc*8+nc
            const int u = t;
            const int f = u >> 6, l = u & 63;
            const int kc = f >> 3, nc = f & 7;
            const int krow = kc * 32 + (l >> 4) * 8;
            const int col  = nc * 16 + (l & 15);
            u16x8 o;
            #pragma unroll
            for (int i = 0; i < 8; ++i) o[i] = f2bf(W1[(size_t)(krow + i) * 128 + col]);
            *(u16x8*)(W1p + (size_t)u * 8) = o;
        } else if (t < r2) {
            const int u = t - r1;
            const int f = u >> 6, l = u & 63;
            const int kc = f >> 2, nc = f & 3;
            const int krow = kc * 32 + (l >> 4) * 8;
            const int col  = nc * 16 + (l & 15);
            u16x8 o;
            #pragma unroll
            for (int i = 0; i < 8; ++i) o[i] = f2bf(W2[(size_t)(krow + i) * 64 + col]);
            *(u16x8*)(W2p + (size_t)u * 8) = o;
        } else {
            const int u = t - r2;
            const int side = u / (B + 1);
            const int b = u - side * (B + 1);
            const int* bat = side ? bbatch : wbatch;
            segs[u] = lower_bound_i(bat, n_act, b);
        }
    }
}

// Accum from f32 tables, XCD-sliced.
// bid = side*(nchunk*8) + chunk*8 + slice; XCD = bid&7 = slice, sides
// temporally separated (per-XCD live line-set = 5.25 MB).
// Block 256 = 4 waves x 8 batches/wave. Lane: rg=lane>>3 picks the batch,
// cl=lane&7 picks 4 f32 cols (float4, 16B). Each 8-lane group owns one
// batch's 32-col slice end-to-end (no cross-lane reduction). 8-deep unroll.
__global__ __launch_bounds__(256)
void nnue_accum_f32s(const int* __restrict__ widx, const int* __restrict__ bidx,
                     const int* __restrict__ stm,
                     const float* __restrict__ wemb, const float* __restrict__ bemb,
                     const int* __restrict__ segs,
                     unsigned short* __restrict__ x16, int B, int nchunk)
{
    const int wave = threadIdx.x >> 6, lane = threadIdx.x & 63;
    const int slice = blockIdx.x & 7;
    const int rest  = blockIdx.x >> 3;
    const int side  = (rest >= nchunk) ? 1 : 0;
    const int chunk = rest - side * nchunk;

    const int rg = lane >> 3, cl = lane & 7;
    const int b  = chunk * 32 + wave * 8 + rg;

    const int* __restrict__ idx = side ? bidx : widx;
    const float* __restrict__ sp =
        (side ? bemb : wemb) + slice * 32 + cl * 4;
    const int* __restrict__ sg = segs + side * (B + 1);

    const int rs = sg[b], re = sg[b + 1];

    float4 s = make_float4(0.f, 0.f, 0.f, 0.f);
    int r = rs;
    for (; r + 8 <= re; r += 8) {
        const int i0 = idx[r],     i1 = idx[r + 1], i2 = idx[r + 2], i3 = idx[r + 3];
        const int i4 = idx[r + 4], i5 = idx[r + 5], i6 = idx[r + 6], i7 = idx[r + 7];
        const float4 v0 = *(const float4*)(sp + (size_t)i0 * 256);
        const float4 v1 = *(const float4*)(sp + (size_t)i1 * 256);
        const float4 v2 = *(const float4*)(sp + (size_t)i2 * 256);
        const float4 v3 = *(const float4*)(sp + (size_t)i3 * 256);
        const float4 v4 = *(const float4*)(sp + (size_t)i4 * 256);
        const float4 v5 = *(const float4*)(sp + (size_t)i5 * 256);
        const float4 v6 = *(const float4*)(sp + (size_t)i6 * 256);
        const float4 v7 = *(const float4*)(sp + (size_t)i7 * 256);
        s.x += v0.x; s.y += v0.y; s.z += v0.z; s.w += v0.w;
        s.x += v1.x; s.y += v1.y; s.z += v1.z; s.w += v1.w;
        s.x += v2.x; s.y += v2.y; s.z += v2.z; s.w += v2.w;
        s.x += v3.x; s.y += v3.y; s.z += v3.z; s.w += v3.w;
        s.x += v4.x; s.y += v4.y; s.z += v4.z; s.w += v4.w;
        s.x += v5.x; s.y += v5.y; s.z += v5.z; s.w += v5.w;
        s.x += v6.x; s.y += v6.y; s.z += v6.z; s.w += v6.w;
        s.x += v7.x; s.y += v7.y; s.z += v7.z; s.w += v7.w;
    }
    for (; r + 4 <= re; r += 4) {
        const int i0 = idx[r], i1 = idx[r + 1], i2 = idx[r + 2], i3 = idx[r + 3];
        const float4 v0 = *(const float4*)(sp + (size_t)i0 * 256);
        const float4 v1 = *(const float4*)(sp + (size_t)i1 * 256);
        const float4 v2 = *(const float4*)(sp + (size_t)i2 * 256);
        const float4 v3 = *(const float4*)(sp + (size_t)i3 * 256);
        s.x += v0.x; s.y += v0.y; s.z += v0.z; s.w += v0.w;
        s.x += v1.x; s.y += v1.y; s.z += v1.z; s.w += v1.w;
        s.x += v2.x; s.y += v2.y; s.z += v2.z; s.w += v2.w;
        s.x += v3.x; s.y += v3.y; s.z += v3.z; s.w += v3.w;
    }
    for (; r < re; ++r) {
        const float4 v0 = *(const float4*)(sp + (size_t)idx[r] * 256);
        s.x += v0.x; s.y += v0.y; s.z += v0.z; s.w += v0.w;
    }

    const int off = (stm[b] == 0) ? (side ? 0 : 256) : (side ? 256 : 0);
    ushort4 o;
    o.x = f2bf(s.x); o.y = f2bf(s.y); o.z = f2bf(s.z); o.w = f2bf(s.w);
    *(ushort4*)(x16 + (size_t)b * 512 + off + slice * 32 + cl * 4) = o;
}

// Fused MLP: layer1 (512->128) + layer2 (128->64) via bf16 MFMA,
// layer3 (64->32) + output dot on VALU. 32 rows/block, 4 waves.
__global__ __launch_bounds__(256)
void nnue_mlp16(const unsigned short* __restrict__ x16,
                const unsigned short* __restrict__ W1p, const float* __restrict__ b1,
                const unsigned short* __restrict__ W2p, const float* __restrict__ b2,
                const float* __restrict__ W3, const float* __restrict__ b3,
                const float* __restrict__ Wo, const float* __restrict__ bo,
                float* __restrict__ out, int B)
{
    __shared__ unsigned short h1s[32 * 128];  // bf16, XOR-swizzled 16B granules
    __shared__ float h2s[32][68];             // f32, padded
    __shared__ float W3s[64 * 32];

    const int tid = threadIdx.x, wave = tid >> 6, lane = tid & 63;
    const int row0 = blockIdx.x * 32;
    const int m = lane & 15, kg = lane >> 4;

    for (int i = tid; i < 64 * 32; i += 256) W3s[i] = W3[i];

    // ---- Layer 1: wave (wr, wc) computes rows [16wr,+16) x cols [64wc,+64)
    {
        const int wr = wave >> 1, wc = wave & 1;
        f32x4 acc[4] = {{0,0,0,0},{0,0,0,0},{0,0,0,0},{0,0,0,0}};
        const unsigned short* xrow = x16 + (size_t)(row0 + wr * 16 + m) * 512;
        #pragma unroll
        for (int kc = 0; kc < 16; ++kc) {
            const bf16x8 a = *(const bf16x8*)(xrow + kc * 32 + kg * 8);
            #pragma unroll
            for (int nc = 0; nc < 4; ++nc) {
                const bf16x8 bb = *(const bf16x8*)(W1p + (size_t)((kc * 8 + wc * 4 + nc) * 64 + lane) * 8);
                acc[nc] = __builtin_amdgcn_mfma_f32_16x16x32_bf16(a, bb, acc[nc], 0, 0, 0);
            }
        }
        #pragma unroll
        for (int nc = 0; nc < 4; ++nc) {
            const int col = wc * 64 + nc * 16 + m;
            const float bias = b1[col];
            #pragma unroll
            for (int reg = 0; reg < 4; ++reg) {
                const int row = wr * 16 + kg * 4 + reg;
                const float v = fmaxf(acc[nc][reg] + bias, 0.f);
                h1s[row * 128 + (((col >> 3) ^ (row & 15)) << 3) + (col & 7)] = f2bf(v);
            }
        }
    }
    __syncthreads();

    // ---- Layer 2: wave (mr, wc2): rows [16mr,+16) x cols [32wc2,+32), K=128
    {
        const int mr = wave >> 1, wc2 = wave & 1;
        f32x4 acc2[2] = {{0,0,0,0},{0,0,0,0}};
        const int row = mr * 16 + m;
        #pragma unroll
        for (int kc = 0; kc < 4; ++kc) {
            const int g = (kc * 4 + kg) ^ (row & 15);
            const bf16x8 a = *(const bf16x8*)&h1s[row * 128 + g * 8];
            #pragma unroll
            for (int ncl = 0; ncl < 2; ++ncl) {
                const bf16x8 bb = *(const bf16x8*)(W2p + (size_t)((kc * 4 + wc2 * 2 + ncl) * 64 + lane) * 8);
                acc2[ncl] = __builtin_amdgcn_mfma_f32_16x16x32_bf16(a, bb, acc2[ncl], 0, 0, 0);
            }
        }
        #pragma unroll
        for (int ncl = 0; ncl < 2; ++ncl) {
            const int col2 = wc2 * 32 + ncl * 16 + m;
            const float bias = b2[col2];
            #pragma unroll
            for (int reg = 0; reg < 4; ++reg) {
                const int row2 = mr * 16 + kg * 4 + reg;
                h2s[row2][col2] = fmaxf(acc2[ncl][reg] + bias, 0.f);
            }
        }
    }
    __syncthreads();

    // ---- Layer 3 + output
    {
        const int col3 = lane & 31, rsel = lane >> 5;
        const int rbase = wave * 8 + rsel * 4;
        float acc3[4];
        const float bias3 = b3[col3];
        #pragma unroll
        for (int ri = 0; ri < 4; ++ri) acc3[ri] = bias3;
        #pragma unroll
        for (int k = 0; k < 64; k += 4) {
            float4 w;
            w.x = W3s[(k + 0) * 32 + col3];
            w.y = W3s[(k + 1) * 32 + col3];
            w.z = W3s[(k + 2) * 32 + col3];
            w.w = W3s[(k + 3) * 32 + col3];
            #pragma unroll
            for (int ri = 0; ri < 4; ++ri) {
                const float4 h = *(const float4*)&h2s[rbase + ri][k];
                acc3[ri] = fmaf(h.x, w.x, fmaf(h.y, w.y, fmaf(h.z, w.z, fmaf(h.w, w.w, acc3[ri]))));
            }
        }
        const float wo = Wo[col3], bo0 = bo[0];
        #pragma unroll
        for (int ri = 0; ri < 4; ++ri) {
            float v = fmaxf(acc3[ri], 0.f) * wo;
            v += __shfl_xor(v, 16, 64);
            v += __shfl_xor(v, 8, 64);
            v += __shfl_xor(v, 4, 64);
            v += __shfl_xor(v, 2, 64);
            v += __shfl_xor(v, 1, 64);
            if (col3 == 0) out[row0 + rbase + ri] = v + bo0;
        }
    }
}

// ===========================================================================
// FALLBACK (f32 path, used only if ws_size is too small or B%32 != 0)
// ===========================================================================

__global__ __launch_bounds__(64)
void nnue_accum_f32(const int* __restrict__ widx, const int* __restrict__ bidx,
                    const int* __restrict__ wbatch, const int* __restrict__ bbatch,
                    const int* __restrict__ stm,
                    const float* __restrict__ wemb, const float* __restrict__ bemb,
                    float* __restrict__ x, int n_act)
{
    const int b = blockIdx.x, side = blockIdx.y;
    const int*   __restrict__ idx   = side ? bidx   : widx;
    const int*   __restrict__ batch = side ? bbatch : wbatch;
    const float* __restrict__ emb   = side ? bemb   : wemb;
    const int start = lower_bound_i(batch, n_act, b);
    const int end   = lower_bound_i(batch, n_act, b + 1);
    const int c = threadIdx.x << 2;
    float4 s0 = make_float4(0.f, 0.f, 0.f, 0.f);
    float4 s1 = s0, s2 = s0, s3 = s0;
    int r = start;
    for (; r + 4 <= end; r += 4) {
        const float4 v0 = *(const float4*)(emb + (size_t)idx[r + 0] * 256 + c);
        const float4 v1 = *(const float4*)(emb + (size_t)idx[r + 1] * 256 + c);
        const float4 v2 = *(const float4*)(emb + (size_t)idx[r + 2] * 256 + c);
        const float4 v3 = *(const float4*)(emb + (size_t)idx[r + 3] * 256 + c);
        s0.x += v0.x; s0.y += v0.y; s0.z += v0.z; s0.w += v0.w;
        s1.x += v1.x; s1.y += v1.y; s1.z += v1.z; s1.w += v1.w;
        s2.x += v2.x; s2.y += v2.y; s2.z += v2.z; s2.w += v2.w;
        s3.x += v3.x; s3.y += v3.y; s3.z += v3.z; s3.w += v3.w;
    }
    for (; r < end; ++r) {
        const float4 v0 = *(const float4*)(emb + (size_t)idx[r] * 256 + c);
        s0.x += v0.x; s0.y += v0.y; s0.z += v0.z; s0.w += v0.w;
    }
    s0.x += s1.x + s2.x + s3.x; s0.y += s1.y + s2.y + s3.y;
    s0.z += s1.z + s2.z + s3.z; s0.w += s1.w + s2.w + s3.w;
    const int off = (stm[b] == 0) ? (side ? 0 : 256) : (side ? 256 : 0);
    *(float4*)(x + (size_t)b * 512 + off + c) = s0;
}

__global__ __launch_bounds__(256)
void nnue_layer1_f32(const float* __restrict__ x, const float* __restrict__ W1,
                     const float* __restrict__ b1, float* __restrict__ h1, int B)
{
    __shared__ float xs[16][512];
    const int tid = threadIdx.x;
    const int row0 = blockIdx.x * 16;
    #pragma unroll
    for (int i = 0; i < 8; ++i) {
        const int e = (i * 256 + tid) * 4;
        const int rr = e >> 9, cc = e & 511;
        if (row0 + rr < B)
            *(float4*)&xs[rr][cc] = *(const float4*)(x + (size_t)(row0 + rr) * 512 + cc);
    }
    __syncthreads();
    const int wave = tid >> 6, lane = tid & 63;
    const int j2 = lane * 2, wrow = wave * 4;
    float2 acc[4];
    #pragma unroll
    for (int r2 = 0; r2 < 4; ++r2) { acc[r2].x = b1[j2]; acc[r2].y = b1[j2 + 1]; }
    for (int k = 0; k < 512; k += 4) {
        float4 xv[4];
        #pragma unroll
        for (int r2 = 0; r2 < 4; ++r2) xv[r2] = *(const float4*)&xs[wrow + r2][k];
        #pragma unroll
        for (int kk = 0; kk < 4; ++kk) {
            const float2 w = *(const float2*)(W1 + (size_t)(k + kk) * 128 + j2);
            #pragma unroll
            for (int r2 = 0; r2 < 4; ++r2) {
                const float xvv = (&xv[r2].x)[kk];
                acc[r2].x = fmaf(xvv, w.x, acc[r2].x);
                acc[r2].y = fmaf(xvv, w.y, acc[r2].y);
            }
        }
    }
    #pragma unroll
    for (int r2 = 0; r2 < 4; ++r2) {
        const int row = row0 + wrow + r2;
        if (row < B) {
            float2 o;
            o.x = fmaxf(acc[r2].x, 0.f); o.y = fmaxf(acc[r2].y, 0.f);
            *(float2*)(h1 + (size_t)row * 128 + j2) = o;
        }
    }
}

__global__ __launch_bounds__(256)
void nnue_tail_f32(const float* __restrict__ h1,
                   const float* __restrict__ W2, const float* __restrict__ b2,
                   const float* __restrict__ W3, const float* __restrict__ b3,
                   const float* __restrict__ Wo, const float* __restrict__ bo,
                   float* __restrict__ out, int B)
{
    __shared__ float W2s[128 * 64];
    __shared__ float W3s[64 * 32];
    __shared__ float Wos[32];
    __shared__ float h1row[4][128];
    __shared__ float h2row[4][64];
    const int tid = threadIdx.x;
    for (int i = tid; i < 128 * 64; i += 256) W2s[i] = W2[i];
    for (int i = tid; i < 64 * 32; i += 256)  W3s[i] = W3[i];
    if (tid < 32) Wos[tid] = Wo[tid];
    __syncthreads();
    const int wave = tid >> 6, lane = tid & 63;
    const float bias2 = b2[lane];
    const float bias3 = (lane < 32) ? b3[lane] : 0.f;
    const float wo = (lane < 32) ? Wos[lane] : 0.f;
    const float bo0 = bo[0];
    #pragma unroll 1
    for (int it = 0; it < 8; ++it) {
        const int row = blockIdx.x * 32 + wave * 8 + it;
        if (row >= B) break;
        h1row[wave][lane]      = h1[(size_t)row * 128 + lane];
        h1row[wave][lane + 64] = h1[(size_t)row * 128 + 64 + lane];
        float acc = bias2;
        #pragma unroll 8
        for (int k = 0; k < 128; ++k)
            acc = fmaf(h1row[wave][k], W2s[k * 64 + lane], acc);
        acc = fmaxf(acc, 0.f);
        h2row[wave][lane] = acc;
        float acc3 = 0.f;
        if (lane < 32) {
            acc3 = bias3;
            #pragma unroll 8
            for (int k = 0; k < 64; ++k)
                acc3 = fmaf(h2row[wave][k], W3s[k * 32 + lane], acc3);
            acc3 = fmaxf(acc3, 0.f) * wo;
        }
        #pragma unroll
        for (int sft = 32; sft >= 1; sft >>= 1)
            acc3 += __shfl_xor(acc3, sft, 64);
        if (lane == 0) out[row] = acc3 + bo0;
    }
}

// ===========================================================================

extern "C" void kernel_launch(void* const* d_in, const int* in_sizes, int n_in,
                              void* d_out, int out_size, void* d_ws, size_t ws_size,
                              hipStream_t stream)
{
    const int*   widx   = (const int*)d_in[0];
    const int*   bidx   = (const int*)d_in[1];
    const int*   wbatch = (const int*)d_in[2];
    const int*   bbatch = (const int*)d_in[3];
    const int*   stm    = (const int*)d_in[4];
    const float* wemb   = (const float*)d_in[5];
    const float* bemb   = (const float*)d_in[6];
    const float* W1     = (const float*)d_in[7];
    const float* b1     = (const float*)d_in[8];
    const float* W2     = (const float*)d_in[9];
    const float* b2     = (const float*)d_in[10];
    const float* W3     = (const float*)d_in[11];
    const float* b3     = (const float*)d_in[12];
    const float* Wo     = (const float*)d_in[13];
    const float* bo     = (const float*)d_in[14];

    const int n_act = in_sizes[0];
    const int B     = in_sizes[4];

    // workspace layout (fast path) — no table buffers anymore
    char* p = (char*)d_ws;
    unsigned short* x16 = (unsigned short*)p; p += (size_t)B * 512 * 2;
    unsigned short* W1p = (unsigned short*)p; p += 65536 * 2;
    unsigned short* W2p = (unsigned short*)p; p += 8192 * 2;
    int*            segs = (int*)p;           p += (size_t)2 * (B + 1) * 4;
    const size_t needed = (size_t)(p - (char*)d_ws);

    const bool fast = (ws_size >= needed) && (B % 32) == 0;

    if (fast) {
        nnue_prep_lite<<<128, 256, 0, stream>>>(W1, W2, wbatch, bbatch,
                                                W1p, W2p, segs, n_act, B);
        // bid = side*(nchunk*8) + chunk*8 + slice; XCD = bid&7 = slice
        const int nchunk = B / 32;
        const int nblk = 2 * nchunk * NSLICE;
        nnue_accum_f32s<<<nblk, 256, 0, stream>>>(widx, bidx, stm, wemb, bemb,
                                                  segs, x16, B, nchunk);
        nnue_mlp16<<<B / 32, 256, 0, stream>>>(x16, W1p, b1, W2p, b2,
                                               W3, b3, Wo, bo, (float*)d_out, B);
    } else {
        float* x  = (float*)d_ws;
        float* h1 = x + (size_t)B * 512;
        dim3 gA(B, 2);
        nnue_accum_f32<<<gA, 64, 0, stream>>>(widx, bidx, wbatch, bbatch, stm,
                                              wemb, bemb, x, n_act);
        nnue_layer1_f32<<<(B + 15) / 16, 256, 0, stream>>>(x, W1, b1, h1, B);
        nnue_tail_f32<<<(B + 31) / 32, 256, 0, stream>>>(h1, W2, b2, W3, b3, Wo, bo,
                                                         (float*)d_out, B);
    }
}

// Round 6
// 71.378 us; speedup vs baseline: 1.3945x; 1.0071x over previous
//
#include <hip/hip_runtime.h>
#include <hip/hip_bf16.h>

using bf16x8 = __attribute__((ext_vector_type(8))) short;
using f32x4  = __attribute__((ext_vector_type(4))) float;
using u16x8  = __attribute__((ext_vector_type(8))) unsigned short;

static __device__ __forceinline__ float bf2f(unsigned short u) {
    union { unsigned int i; float f; } v; v.i = ((unsigned int)u) << 16; return v.f;
}
static __device__ __forceinline__ unsigned short f2bf(float f) {
    __hip_bfloat16 h = __float2bfloat16(f);
    return *reinterpret_cast<unsigned short*>(&h);
}

__device__ __forceinline__ int lower_bound_i(const int* __restrict__ a, int n, int v) {
    int lo = 0, hi = n;
    while (lo < hi) {
        int mid = (lo + hi) >> 1;
        if (a[mid] < v) lo = mid + 1; else hi = mid;
    }
    return lo;
}

// ===========================================================================
// FAST PATH
// ===========================================================================
// Table layout after prep (per side): 8 slabs of 32 columns, slice-major:
//   emb16[slice][row][32]  (slab = 40960*32 u16 = 2.62 MB -> fits 4MB XCD L2)

#define NROW 40960
#define NSLICE 8
#define SLICEW 32   // bf16 columns per slice

// Prep: f32->bf16 slice-major tables, MFMA-packed W1/W2, segment bounds.
__global__ __launch_bounds__(256)
void nnue_prep(const float* __restrict__ wemb, const float* __restrict__ bemb,
               const float* __restrict__ W1, const float* __restrict__ W2,
               const int* __restrict__ wbatch, const int* __restrict__ bbatch,
               unsigned short* __restrict__ wemb16, unsigned short* __restrict__ bemb16,
               unsigned short* __restrict__ W1p, unsigned short* __restrict__ W2p,
               int* __restrict__ segs, long long groups, int n_act, int B)
{
    const long long r0 = groups;            // wemb groups (8 elems each)
    const long long r1 = 2 * groups;        // bemb groups
    const long long r2 = r1 + 8192;         // W1p groups: 128 frags x 64 lanes
    const long long r3 = r2 + 1024;         // W2p groups: 16 frags x 64 lanes
    const long long r4 = r3 + 2LL * (B + 1);// seg bounds
    const long long stride = (long long)gridDim.x * blockDim.x;

    for (long long t = (long long)blockIdx.x * blockDim.x + threadIdx.x;
         t < r4; t += stride) {
        if (t < r1) {
            const int w = (t < r0);
            const long long g = w ? t : (t - r0);
            const float* src = (w ? wemb : bemb) + g * 8;
            const int row  = (int)(g >> 5);
            const int col0 = ((int)g & 31) * 8;
            unsigned short* dst = (w ? wemb16 : bemb16)
                + (size_t)(col0 >> 5) * NROW * SLICEW
                + (size_t)row * SLICEW + (col0 & 31);
            const float4 a = *(const float4*)(src);
            const float4 b = *(const float4*)(src + 4);
            u16x8 o;
            o[0] = f2bf(a.x); o[1] = f2bf(a.y); o[2] = f2bf(a.z); o[3] = f2bf(a.w);
            o[4] = f2bf(b.x); o[5] = f2bf(b.y); o[6] = f2bf(b.z); o[7] = f2bf(b.w);
            *(u16x8*)dst = o;
        } else if (t < r2) {
            // W1p[(f*64+l)*8+i] = bf16(W1[kc*32+(l>>4)*8+i][nc*16+(l&15)]), f=kc*8+nc
            const int u = (int)(t - r1);
            const int f = u >> 6, l = u & 63;
            const int kc = f >> 3, nc = f & 7;
            const int krow = kc * 32 + (l >> 4) * 8;
            const int col  = nc * 16 + (l & 15);
            u16x8 o;
            #pragma unroll
            for (int i = 0; i < 8; ++i) o[i] = f2bf(W1[(size_t)(krow + i) * 128 + col]);
            *(u16x8*)(W1p + (size_t)u * 8) = o;
        } else if (t < r3) {
            const int u = (int)(t - r2);
            const int f = u >> 6, l = u & 63;
            const int kc = f >> 2, nc = f & 3;
            const int krow = kc * 32 + (l >> 4) * 8;
            const int col  = nc * 16 + (l & 15);
            u16x8 o;
            #pragma unroll
            for (int i = 0; i < 8; ++i) o[i] = f2bf(W2[(size_t)(krow + i) * 64 + col]);
            *(u16x8*)(W2p + (size_t)u * 8) = o;
        } else {
            const int u = (int)(t - r3);
            const int side = u / (B + 1);
            const int b = u - side * (B + 1);
            const int* bat = side ? bbatch : wbatch;
            segs[u] = lower_bound_i(bat, n_act, b);
        }
    }
}

// Accum, XCD-sliced, idx-pack pipelined.
// bid = side*(nchunk*8) + chunk*8 + slice; XCD = bid&7 = slice, sides
// temporally separated (per-XCD live slab = 2.62 MB, L2-resident).
// Block 256 = 4 waves x 8 batches/wave. Group rg=lane>>3 owns one batch,
// lanes cl=lane&7 cover its 64B row-slice. Per 8-row pack: ONE coalesced idx
// load (lane cl -> idx[r+cl]), intra-group __shfl broadcast, 8 independent
// gathers in flight; next pack's idx prefetched under the gathers.
__global__ __launch_bounds__(256)
void nnue_accum16p(const int* __restrict__ widx, const int* __restrict__ bidx,
                   const int* __restrict__ stm,
                   const unsigned short* __restrict__ wemb16,
                   const unsigned short* __restrict__ bemb16,
                   const int* __restrict__ segs,
                   unsigned short* __restrict__ x16, int B, int nchunk)
{
    const int wave = threadIdx.x >> 6, lane = threadIdx.x & 63;
    const int slice = blockIdx.x & 7;
    const int rest  = blockIdx.x >> 3;
    const int side  = (rest >= nchunk) ? 1 : 0;
    const int chunk = rest - side * nchunk;

    const int rg = lane >> 3, cl = lane & 7;
    const int gb = rg << 3;                 // group lane base
    const int b  = chunk * 32 + wave * 8 + rg;

    const int* __restrict__ idx = side ? bidx : widx;
    const unsigned short* __restrict__ sp =
        (side ? bemb16 : wemb16) + (size_t)slice * NROW * SLICEW + cl * 4;
    const int* __restrict__ sg = segs + side * (B + 1);

    const int rs = sg[b], re = sg[b + 1];

    float4 s0 = make_float4(0.f, 0.f, 0.f, 0.f);
    float4 s1 = s0;

    int r = rs;
    int pk = 0;
    if (r + 8 <= re) pk = idx[r + cl];      // first idx pack (coalesced 32B/group)
    while (r + 8 <= re) {
        const int cur = pk;
        const int rn = r + 8;
        if (rn + 8 <= re) pk = idx[rn + cl];   // prefetch next pack
        int iu[8];
        #pragma unroll
        for (int u = 0; u < 8; ++u) iu[u] = __shfl(cur, gb + u, 64);
        ushort4 v[8];
        #pragma unroll
        for (int u = 0; u < 8; ++u)
            v[u] = *(const ushort4*)(sp + (size_t)iu[u] * SLICEW);
        #pragma unroll
        for (int u = 0; u < 8; u += 2) {
            s0.x += bf2f(v[u].x);     s0.y += bf2f(v[u].y);
            s0.z += bf2f(v[u].z);     s0.w += bf2f(v[u].w);
            s1.x += bf2f(v[u + 1].x); s1.y += bf2f(v[u + 1].y);
            s1.z += bf2f(v[u + 1].z); s1.w += bf2f(v[u + 1].w);
        }
        r = rn;
    }
    for (; r < re; ++r) {                    // tail < 8 rows
        const ushort4 v = *(const ushort4*)(sp + (size_t)idx[r] * SLICEW);
        s0.x += bf2f(v.x); s0.y += bf2f(v.y); s0.z += bf2f(v.z); s0.w += bf2f(v.w);
    }
    s0.x += s1.x; s0.y += s1.y; s0.z += s1.z; s0.w += s1.w;

    const int off = (stm[b] == 0) ? (side ? 0 : 256) : (side ? 256 : 0);
    ushort4 o;
    o.x = f2bf(s0.x); o.y = f2bf(s0.y); o.z = f2bf(s0.z); o.w = f2bf(s0.w);
    *(ushort4*)(x16 + (size_t)b * 512 + off + slice * SLICEW + cl * 4) = o;
}

// Fused MLP: layer1 (512->128) + layer2 (128->64) via bf16 MFMA,
// layer3 (64->32) + output dot on VALU. 32 rows/block, 4 waves.
__global__ __launch_bounds__(256)
void nnue_mlp16(const unsigned short* __restrict__ x16,
                const unsigned short* __restrict__ W1p, const float* __restrict__ b1,
                const unsigned short* __restrict__ W2p, const float* __restrict__ b2,
                const float* __restrict__ W3, const float* __restrict__ b3,
                const float* __restrict__ Wo, const float* __restrict__ bo,
                float* __restrict__ out, int B)
{
    __shared__ unsigned short h1s[32 * 128];  // bf16, XOR-swizzled 16B granules
    __shared__ float h2s[32][68];             // f32, padded
    __shared__ float W3s[64 * 32];

    const int tid = threadIdx.x, wave = tid >> 6, lane = tid & 63;
    const int row0 = blockIdx.x * 32;
    const int m = lane & 15, kg = lane >> 4;

    for (int i = tid; i < 64 * 32; i += 256) W3s[i] = W3[i];

    // ---- Layer 1: wave (wr, wc) computes rows [16wr,+16) x cols [64wc,+64)
    {
        const int wr = wave >> 1, wc = wave & 1;
        f32x4 acc[4] = {{0,0,0,0},{0,0,0,0},{0,0,0,0},{0,0,0,0}};
        const unsigned short* xrow = x16 + (size_t)(row0 + wr * 16 + m) * 512;
        #pragma unroll
        for (int kc = 0; kc < 16; ++kc) {
            const bf16x8 a = *(const bf16x8*)(xrow + kc * 32 + kg * 8);
            #pragma unroll
            for (int nc = 0; nc < 4; ++nc) {
                const bf16x8 bb = *(const bf16x8*)(W1p + (size_t)((kc * 8 + wc * 4 + nc) * 64 + lane) * 8);
                acc[nc] = __builtin_amdgcn_mfma_f32_16x16x32_bf16(a, bb, acc[nc], 0, 0, 0);
            }
        }
        #pragma unroll
        for (int nc = 0; nc < 4; ++nc) {
            const int col = wc * 64 + nc * 16 + m;
            const float bias = b1[col];
            #pragma unroll
            for (int reg = 0; reg < 4; ++reg) {
                const int row = wr * 16 + kg * 4 + reg;
                const float v = fmaxf(acc[nc][reg] + bias, 0.f);
                h1s[row * 128 + (((col >> 3) ^ (row & 15)) << 3) + (col & 7)] = f2bf(v);
            }
        }
    }
    __syncthreads();

    // ---- Layer 2: wave (mr, wc2): rows [16mr,+16) x cols [32wc2,+32), K=128
    {
        const int mr = wave >> 1, wc2 = wave & 1;
        f32x4 acc2[2] = {{0,0,0,0},{0,0,0,0}};
        const int row = mr * 16 + m;
        #pragma unroll
        for (int kc = 0; kc < 4; ++kc) {
            const int g = (kc * 4 + kg) ^ (row & 15);
            const bf16x8 a = *(const bf16x8*)&h1s[row * 128 + g * 8];
            #pragma unroll
            for (int ncl = 0; ncl < 2; ++ncl) {
                const bf16x8 bb = *(const bf16x8*)(W2p + (size_t)((kc * 4 + wc2 * 2 + ncl) * 64 + lane) * 8);
                acc2[ncl] = __builtin_amdgcn_mfma_f32_16x16x32_bf16(a, bb, acc2[ncl], 0, 0, 0);
            }
        }
        #pragma unroll
        for (int ncl = 0; ncl < 2; ++ncl) {
            const int col2 = wc2 * 32 + ncl * 16 + m;
            const float bias = b2[col2];
            #pragma unroll
            for (int reg = 0; reg < 4; ++reg) {
                const int row2 = mr * 16 + kg * 4 + reg;
                h2s[row2][col2] = fmaxf(acc2[ncl][reg] + bias, 0.f);
            }
        }
    }
    __syncthreads();

    // ---- Layer 3 + output
    {
        const int col3 = lane & 31, rsel = lane >> 5;
        const int rbase = wave * 8 + rsel * 4;
        float acc3[4];
        const float bias3 = b3[col3];
        #pragma unroll
        for (int ri = 0; ri < 4; ++ri) acc3[ri] = bias3;
        #pragma unroll
        for (int k = 0; k < 64; k += 4) {
            float4 w;
            w.x = W3s[(k + 0) * 32 + col3];
            w.y = W3s[(k + 1) * 32 + col3];
            w.z = W3s[(k + 2) * 32 + col3];
            w.w = W3s[(k + 3) * 32 + col3];
            #pragma unroll
            for (int ri = 0; ri < 4; ++ri) {
                const float4 h = *(const float4*)&h2s[rbase + ri][k];
                acc3[ri] = fmaf(h.x, w.x, fmaf(h.y, w.y, fmaf(h.z, w.z, fmaf(h.w, w.w, acc3[ri]))));
            }
        }
        const float wo = Wo[col3], bo0 = bo[0];
        #pragma unroll
        for (int ri = 0; ri < 4; ++ri) {
            float v = fmaxf(acc3[ri], 0.f) * wo;
            v += __shfl_xor(v, 16, 64);
            v += __shfl_xor(v, 8, 64);
            v += __shfl_xor(v, 4, 64);
            v += __shfl_xor(v, 2, 64);
            v += __shfl_xor(v, 1, 64);
            if (col3 == 0) out[row0 + rbase + ri] = v + bo0;
        }
    }
}

// ===========================================================================
// FALLBACK (f32 path, used only if ws_size is too small or B%32 != 0)
// ===========================================================================

__global__ __launch_bounds__(64)
void nnue_accum_f32(const int* __restrict__ widx, const int* __restrict__ bidx,
                    const int* __restrict__ wbatch, const int* __restrict__ bbatch,
                    const int* __restrict__ stm,
                    const float* __restrict__ wemb, const float* __restrict__ bemb,
                    float* __restrict__ x, int n_act)
{
    const int b = blockIdx.x, side = blockIdx.y;
    const int*   __restrict__ idx   = side ? bidx   : widx;
    const int*   __restrict__ batch = side ? bbatch : wbatch;
    const float* __restrict__ emb   = side ? bemb   : wemb;
    const int start = lower_bound_i(batch, n_act, b);
    const int end   = lower_bound_i(batch, n_act, b + 1);
    const int c = threadIdx.x << 2;
    float4 s0 = make_float4(0.f, 0.f, 0.f, 0.f);
    float4 s1 = s0, s2 = s0, s3 = s0;
    int r = start;
    for (; r + 4 <= end; r += 4) {
        const float4 v0 = *(const float4*)(emb + (size_t)idx[r + 0] * 256 + c);
        const float4 v1 = *(const float4*)(emb + (size_t)idx[r + 1] * 256 + c);
        const float4 v2 = *(const float4*)(emb + (size_t)idx[r + 2] * 256 + c);
        const float4 v3 = *(const float4*)(emb + (size_t)idx[r + 3] * 256 + c);
        s0.x += v0.x; s0.y += v0.y; s0.z += v0.z; s0.w += v0.w;
        s1.x += v1.x; s1.y += v1.y; s1.z += v1.z; s1.w += v1.w;
        s2.x += v2.x; s2.y += v2.y; s2.z += v2.z; s2.w += v2.w;
        s3.x += v3.x; s3.y += v3.y; s3.z += v3.z; s3.w += v3.w;
    }
    for (; r < end; ++r) {
        const float4 v0 = *(const float4*)(emb + (size_t)idx[r] * 256 + c);
        s0.x += v0.x; s0.y += v0.y; s0.z += v0.z; s0.w += v0.w;
    }
    s0.x += s1.x + s2.x + s3.x; s0.y += s1.y + s2.y + s3.y;
    s0.z += s1.z + s2.z + s3.z; s0.w += s1.w + s2.w + s3.w;
    const int off = (stm[b] == 0) ? (side ? 0 : 256) : (side ? 256 : 0);
    *(float4*)(x + (size_t)b * 512 + off + c) = s0;
}

__global__ __launch_bounds__(256)
void nnue_layer1_f32(const float* __restrict__ x, const float* __restrict__ W1,
                     const float* __restrict__ b1, float* __restrict__ h1, int B)
{
    __shared__ float xs[16][512];
    const int tid = threadIdx.x;
    const int row0 = blockIdx.x * 16;
    #pragma unroll
    for (int i = 0; i < 8; ++i) {
        const int e = (i * 256 + tid) * 4;
        const int rr = e >> 9, cc = e & 511;
        if (row0 + rr < B)
            *(float4*)&xs[rr][cc] = *(const float4*)(x + (size_t)(row0 + rr) * 512 + cc);
    }
    __syncthreads();
    const int wave = tid >> 6, lane = tid & 63;
    const int j2 = lane * 2, wrow = wave * 4;
    float2 acc[4];
    #pragma unroll
    for (int r2 = 0; r2 < 4; ++r2) { acc[r2].x = b1[j2]; acc[r2].y = b1[j2 + 1]; }
    for (int k = 0; k < 512; k += 4) {
        float4 xv[4];
        #pragma unroll
        for (int r2 = 0; r2 < 4; ++r2) xv[r2] = *(const float4*)&xs[wrow + r2][k];
        #pragma unroll
        for (int kk = 0; kk < 4; ++kk) {
            const float2 w = *(const float2*)(W1 + (size_t)(k + kk) * 128 + j2);
            #pragma unroll
            for (int r2 = 0; r2 < 4; ++r2) {
                const float xvv = (&xv[r2].x)[kk];
                acc[r2].x = fmaf(xvv, w.x, acc[r2].x);
                acc[r2].y = fmaf(xvv, w.y, acc[r2].y);
            }
        }
    }
    #pragma unroll
    for (int r2 = 0; r2 < 4; ++r2) {
        const int row = row0 + wrow + r2;
        if (row < B) {
            float2 o;
            o.x = fmaxf(acc[r2].x, 0.f); o.y = fmaxf(acc[r2].y, 0.f);
            *(float2*)(h1 + (size_t)row * 128 + j2) = o;
        }
    }
}

__global__ __launch_bounds__(256)
void nnue_tail_f32(const float* __restrict__ h1,
                   const float* __restrict__ W2, const float* __restrict__ b2,
                   const float* __restrict__ W3, const float* __restrict__ b3,
                   const float* __restrict__ Wo, const float* __restrict__ bo,
                   float* __restrict__ out, int B)
{
    __shared__ float W2s[128 * 64];
    __shared__ float W3s[64 * 32];
    __shared__ float Wos[32];
    __shared__ float h1row[4][128];
    __shared__ float h2row[4][64];
    const int tid = threadIdx.x;
    for (int i = tid; i < 128 * 64; i += 256) W2s[i] = W2[i];
    for (int i = tid; i < 64 * 32; i += 256)  W3s[i] = W3[i];
    if (tid < 32) Wos[tid] = Wo[tid];
    __syncthreads();
    const int wave = tid >> 6, lane = tid & 63;
    const float bias2 = b2[lane];
    const float bias3 = (lane < 32) ? b3[lane] : 0.f;
    const float wo = (lane < 32) ? Wos[lane] : 0.f;
    const float bo0 = bo[0];
    #pragma unroll 1
    for (int it = 0; it < 8; ++it) {
        const int row = blockIdx.x * 32 + wave * 8 + it;
        if (row >= B) break;
        h1row[wave][lane]      = h1[(size_t)row * 128 + lane];
        h1row[wave][lane + 64] = h1[(size_t)row * 128 + 64 + lane];
        float acc = bias2;
        #pragma unroll 8
        for (int k = 0; k < 128; ++k)
            acc = fmaf(h1row[wave][k], W2s[k * 64 + lane], acc);
        acc = fmaxf(acc, 0.f);
        h2row[wave][lane] = acc;
        float acc3 = 0.f;
        if (lane < 32) {
            acc3 = bias3;
            #pragma unroll 8
            for (int k = 0; k < 64; ++k)
                acc3 = fmaf(h2row[wave][k], W3s[k * 32 + lane], acc3);
            acc3 = fmaxf(acc3, 0.f) * wo;
        }
        #pragma unroll
        for (int sft = 32; sft >= 1; sft >>= 1)
            acc3 += __shfl_xor(acc3, sft, 64);
        if (lane == 0) out[row] = acc3 + bo0;
    }
}

// ===========================================================================

extern "C" void kernel_launch(void* const* d_in, const int* in_sizes, int n_in,
                              void* d_out, int out_size, void* d_ws, size_t ws_size,
                              hipStream_t stream)
{
    const int*   widx   = (const int*)d_in[0];
    const int*   bidx   = (const int*)d_in[1];
    const int*   wbatch = (const int*)d_in[2];
    const int*   bbatch = (const int*)d_in[3];
    const int*   stm    = (const int*)d_in[4];
    const float* wemb   = (const float*)d_in[5];
    const float* bemb   = (const float*)d_in[6];
    const float* W1     = (const float*)d_in[7];
    const float* b1     = (const float*)d_in[8];
    const float* W2     = (const float*)d_in[9];
    const float* b2     = (const float*)d_in[10];
    const float* W3     = (const float*)d_in[11];
    const float* b3     = (const float*)d_in[12];
    const float* Wo     = (const float*)d_in[13];
    const float* bo     = (const float*)d_in[14];

    const int n_act = in_sizes[0];
    const int B     = in_sizes[4];
    const size_t embN = (size_t)in_sizes[5];   // 40960*256

    // workspace layout (fast path)
    char* p = (char*)d_ws;
    unsigned short* wemb16 = (unsigned short*)p; p += embN * 2;
    unsigned short* bemb16 = (unsigned short*)p; p += embN * 2;
    unsigned short* x16    = (unsigned short*)p; p += (size_t)B * 512 * 2;
    unsigned short* W1p    = (unsigned short*)p; p += 65536 * 2;
    unsigned short* W2p    = (unsigned short*)p; p += 8192 * 2;
    int*            segs   = (int*)p;            p += (size_t)2 * (B + 1) * 4;
    const size_t needed = (size_t)(p - (char*)d_ws);

    const bool fast = (ws_size >= needed) && (B % 32) == 0 &&
                      embN == (size_t)NROW * 256;

    if (fast) {
        const long long groups = (long long)(embN / 8);
        nnue_prep<<<4096, 256, 0, stream>>>(wemb, bemb, W1, W2, wbatch, bbatch,
                                            wemb16, bemb16, W1p, W2p, segs,
                                            groups, n_act, B);
        // bid = side*(nchunk*8) + chunk*8 + slice; XCD = bid&7 = slice
        const int nchunk = B / 32;
        const int nblk = 2 * nchunk * NSLICE;
        nnue_accum16p<<<nblk, 256, 0, stream>>>(widx, bidx, stm, wemb16, bemb16,
                                                segs, x16, B, nchunk);
        nnue_mlp16<<<B / 32, 256, 0, stream>>>(x16, W1p, b1, W2p, b2,
                                               W3, b3, Wo, bo, (float*)d_out, B);
    } else {
        float* x  = (float*)d_ws;
        float* h1 = x + (size_t)B * 512;
        dim3 gA(B, 2);
        nnue_accum_f32<<<gA, 64, 0, stream>>>(widx, bidx, wbatch, bbatch, stm,
                                              wemb, bemb, x, n_act);
        nnue_layer1_f32<<<(B + 15) / 16, 256, 0, stream>>>(x, W1, b1, h1, B);
        nnue_tail_f32<<<(B + 31) / 32, 256, 0, stream>>>(h1, W2, b2, W3, b3, Wo, bo,
                                                         (float*)d_out, B);
    }
}